// Round 1
// baseline (157.926 us; speedup 1.0000x reference)
//
#include <hip/hip_runtime.h>
#include <hip/hip_bf16.h>

typedef __bf16 bf16_t;
typedef bf16_t bf16x4 __attribute__((ext_vector_type(4)));
typedef bf16_t bf16x8 __attribute__((ext_vector_type(8)));
typedef float  f32x4  __attribute__((ext_vector_type(4)));

constexpr int M_TOT = 65536;   // B*S = 8*8192
constexpr int N_TOT = 512;     // E
constexpr int K_TOT = 512;     // E
constexpr int BM = 128, BN = 128, BK = 64;

// out[m,n] = sum_k cos(x[m,k] + phi[k%8]) * W[n,k] + bias[n]
__global__ __launch_bounds__(256, 2)
void qattn_fused_gemm(const float* __restrict__ x,
                      const float* __restrict__ phi,
                      const float* __restrict__ W,
                      const float* __restrict__ bias,
                      float* __restrict__ out)
{
    __shared__ bf16_t As[BM][BK];   // 16 KB, XOR-swizzled
    __shared__ bf16_t Bs[BN][BK];   // 16 KB, XOR-swizzled

    const int tid  = threadIdx.x;
    const int lane = tid & 63;
    const int wave = tid >> 6;

    // XCD-bijective swizzle: 2048 blocks, 8 XCDs -> 256 per XCD, bn-fastest
    // so the 4 blocks sharing an x-panel are consecutive on ONE XCD (L2 reuse).
    const int xcd = blockIdx.x & 7;
    const int idx = blockIdx.x >> 3;
    const int wid = xcd * 256 + idx;
    const int bm  = (wid >> 2) * BM;   // 512 m-panels
    const int bn  = (wid & 3)  * BN;   // 4 n-panels

    // staging coords: 256 threads cover 16 rows x 16 float4 per pass
    const int srow = tid >> 4;      // 0..15
    const int scol = (tid & 15) * 4;

    // phi index: (k0 + scol + j) % 8 == (scol & 4) + j  (k0, scol multiples of 4/64)
    const int pbase = scol & 4;
    const float p0 = phi[pbase + 0];
    const float p1 = phi[pbase + 1];
    const float p2 = phi[pbase + 2];
    const float p3 = phi[pbase + 3];

    // wave -> 64x64 output quadrant
    const int wm   = (wave >> 1) * 64;
    const int wn   = (wave & 1) * 64;
    const int frow = lane & 15;
    const int fk   = (lane >> 4) * 8;

    f32x4 acc[4][4] = {};

    for (int k0 = 0; k0 < K_TOT; k0 += BK) {
        // ---- stage A = bf16(cos(x+phi)) and B = bf16(W), XOR-swizzled ----
        #pragma unroll
        for (int p = 0; p < 8; ++p) {
            const int row = srow + p * 16;
            const int csw = scol ^ ((row & 7) << 3);

            float4 v = *reinterpret_cast<const float4*>(
                x + (size_t)(bm + row) * K_TOT + k0 + scol);
            bf16x4 a;
            a[0] = (bf16_t)__cosf(v.x + p0);
            a[1] = (bf16_t)__cosf(v.y + p1);
            a[2] = (bf16_t)__cosf(v.z + p2);
            a[3] = (bf16_t)__cosf(v.w + p3);
            *reinterpret_cast<bf16x4*>(&As[row][csw]) = a;

            float4 w = *reinterpret_cast<const float4*>(
                W + (size_t)(bn + row) * K_TOT + k0 + scol);
            bf16x4 b;
            b[0] = (bf16_t)w.x; b[1] = (bf16_t)w.y;
            b[2] = (bf16_t)w.z; b[3] = (bf16_t)w.w;
            *reinterpret_cast<bf16x4*>(&Bs[row][csw]) = b;
        }
        __syncthreads();

        // ---- LDS -> fragments (swizzled ds_read_b128) ----
        bf16x8 af[4][2], bfr[4][2];
        #pragma unroll
        for (int mi = 0; mi < 4; ++mi)
            #pragma unroll
            for (int kk = 0; kk < 2; ++kk) {
                const int r = wm + mi * 16 + frow;
                const int c = (kk * 32 + fk) ^ ((r & 7) << 3);
                af[mi][kk] = *reinterpret_cast<bf16x8*>(&As[r][c]);
            }
        #pragma unroll
        for (int ni = 0; ni < 4; ++ni)
            #pragma unroll
            for (int kk = 0; kk < 2; ++kk) {
                const int r = wn + ni * 16 + frow;
                const int c = (kk * 32 + fk) ^ ((r & 7) << 3);
                bfr[ni][kk] = *reinterpret_cast<bf16x8*>(&Bs[r][c]);
            }

        // ---- 32 MFMAs per wave per K-tile ----
        #pragma unroll
        for (int kk = 0; kk < 2; ++kk)
            #pragma unroll
            for (int mi = 0; mi < 4; ++mi)
                #pragma unroll
                for (int ni = 0; ni < 4; ++ni)
                    acc[mi][ni] = __builtin_amdgcn_mfma_f32_16x16x32_bf16(
                        af[mi][kk], bfr[ni][kk], acc[mi][ni], 0, 0, 0);
        __syncthreads();
    }

    // ---- epilogue: C/D map col=lane&15, row=(lane>>4)*4+i (m89-verified) ----
    #pragma unroll
    for (int ni = 0; ni < 4; ++ni) {
        const int c  = bn + wn + ni * 16 + (lane & 15);
        const float bv = bias[c];
        #pragma unroll
        for (int mi = 0; mi < 4; ++mi) {
            const int r0 = bm + wm + mi * 16 + (lane >> 4) * 4;
            #pragma unroll
            for (int i = 0; i < 4; ++i)
                out[(size_t)(r0 + i) * N_TOT + c] = acc[mi][ni][i] + bv;
        }
    }
}

extern "C" void kernel_launch(void* const* d_in, const int* in_sizes, int n_in,
                              void* d_out, int out_size, void* d_ws, size_t ws_size,
                              hipStream_t stream) {
    const float* x    = (const float*)d_in[0];
    const float* phi  = (const float*)d_in[1];
    const float* W    = (const float*)d_in[2];
    const float* bias = (const float*)d_in[3];
    float* out = (float*)d_out;

    const int grid = (M_TOT / BM) * (N_TOT / BN);   // 2048
    qattn_fused_gemm<<<grid, 256, 0, stream>>>(x, phi, W, bias, out);
}

// Round 2
// 73.677 us; speedup vs baseline: 2.1435x; 2.1435x over previous
//
#include <hip/hip_runtime.h>
#include <hip/hip_bf16.h>

typedef __bf16 bf16_t;
typedef bf16_t bf16x4 __attribute__((ext_vector_type(4)));
typedef bf16_t bf16x8 __attribute__((ext_vector_type(8)));
typedef float  f32x4  __attribute__((ext_vector_type(4)));

constexpr int M_TOT = 65536;   // B*S
constexpr int N_TOT = 512;     // E
constexpr int K_TOT = 512;     // E
constexpr int BM = 128, BN = 128, BK = 64;

__device__ inline void gload_lds16(const void* g, void* l) {
    __builtin_amdgcn_global_load_lds(
        (const __attribute__((address_space(1))) void*)g,
        (__attribute__((address_space(3))) void*)l, 16, 0, 0);
}

// Pre-convert W (f32 [N][K]) -> bf16 in a chunk-XOR-swizzled layout so the main
// kernel can global_load_lds it LINEARLY and read it back with the XOR swizzle.
// W_ws[n][kt*64 + (ck ^ (n&7))*8 + j] = bf16(W[n][kt*64 + ck*8 + j])
__global__ __launch_bounds__(256)
void convert_W(const float* __restrict__ W, bf16_t* __restrict__ Wws)
{
    const int g  = blockIdx.x * 256 + threadIdx.x;  // 32768 chunks of 8 elems
    const int n  = g >> 6;
    const int c  = g & 63;
    const int kt = c >> 3, ck = c & 7;
    const float4* src = reinterpret_cast<const float4*>(W + (size_t)n * K_TOT + c * 8);
    float4 v0 = src[0], v1 = src[1];
    bf16x8 b;
    b[0] = (bf16_t)v0.x; b[1] = (bf16_t)v0.y; b[2] = (bf16_t)v0.z; b[3] = (bf16_t)v0.w;
    b[4] = (bf16_t)v1.x; b[5] = (bf16_t)v1.y; b[6] = (bf16_t)v1.z; b[7] = (bf16_t)v1.w;
    const int dc = kt * 64 + ((ck ^ (n & 7)) * 8);
    *reinterpret_cast<bf16x8*>(Wws + (size_t)n * K_TOT + dc) = b;
}

// out[m,n] = sum_k cos(x[m,k] + phi[k%8]) * W[n,k] + bias[n]
template<bool USE_WS>
__global__ __launch_bounds__(256, 3)
void qattn_fused_gemm(const float* __restrict__ x,
                      const float* __restrict__ phi,
                      const float* __restrict__ W,
                      const bf16_t* __restrict__ Wws,
                      const float* __restrict__ bias,
                      float* __restrict__ out)
{
    __shared__ bf16_t As[BM][BK];   // 16 KB, XOR-swizzled
    __shared__ bf16_t Bs[BN][BK];   // 16 KB, XOR-swizzled image

    const int tid  = threadIdx.x;
    const int lane = tid & 63;
    const int wave = tid >> 6;

    // XCD-bijective swizzle (2048 % 8 == 0): 256 consecutive wids per XCD,
    // bn-fastest so the 4 blocks sharing an x-panel sit on one XCD's L2.
    const int xcd = blockIdx.x & 7;
    const int idx = blockIdx.x >> 3;
    const int wid = xcd * 256 + idx;
    const int bm  = (wid >> 2) * BM;
    const int bn  = (wid & 3)  * BN;

    // staging coords: 256 threads cover 16 rows x 16 float4 per pass
    const int srow = tid >> 4;
    const int scol = (tid & 15) * 4;

    // (k0 + scol + j) % 8 == (scol & 4) + j
    const int pbase = scol & 4;
    const float p0 = phi[pbase + 0];
    const float p1 = phi[pbase + 1];
    const float p2 = phi[pbase + 2];
    const float p3 = phi[pbase + 3];

    const int wm   = (wave >> 1) * 64;
    const int wn   = (wave & 1) * 64;
    const int frow = lane & 15;
    const int fk   = (lane >> 4) * 8;

    f32x4 acc[4][4] = {};

    // ---- prologue: prefetch A tile 0 into registers ----
    float4 pa[8];
    #pragma unroll
    for (int p = 0; p < 8; ++p) {
        const int row = srow + p * 16;
        pa[p] = *reinterpret_cast<const float4*>(x + (size_t)(bm + row) * K_TOT + scol);
    }

    for (int k0 = 0; k0 < K_TOT; k0 += BK) {
        // ---- B: async global->LDS (pre-swizzled source, linear dest) ----
        if (USE_WS) {
            #pragma unroll
            for (int i = 0; i < 4; ++i) {
                const int row   = wave * 32 + i * 8 + (lane >> 3);
                const int chunk = lane & 7;
                const bf16_t* src = Wws + (size_t)(bn + row) * K_TOT + k0 + chunk * 8;
                gload_lds16(src, &Bs[0][0] + wave * 2048 + i * 512);
            }
        } else {
            #pragma unroll
            for (int p = 0; p < 8; ++p) {
                const int row = srow + p * 16;
                const int csw = scol ^ ((row & 7) << 3);
                float4 w = *reinterpret_cast<const float4*>(
                    W + (size_t)(bn + row) * K_TOT + k0 + scol);
                bf16x4 b;
                b[0] = (bf16_t)w.x; b[1] = (bf16_t)w.y;
                b[2] = (bf16_t)w.z; b[3] = (bf16_t)w.w;
                *reinterpret_cast<bf16x4*>(&Bs[row][csw]) = b;
            }
        }

        // ---- A: cos(x+phi) -> bf16 -> LDS from prefetched regs ----
        #pragma unroll
        for (int p = 0; p < 8; ++p) {
            const int row = srow + p * 16;
            const int csw = scol ^ ((row & 7) << 3);
            bf16x4 a;
            a[0] = (bf16_t)__cosf(pa[p].x + p0);
            a[1] = (bf16_t)__cosf(pa[p].y + p1);
            a[2] = (bf16_t)__cosf(pa[p].z + p2);
            a[3] = (bf16_t)__cosf(pa[p].w + p3);
            *reinterpret_cast<bf16x4*>(&As[row][csw]) = a;
        }
        __syncthreads();

        // ---- prefetch next A tile (latency hidden under ds_read+MFMA) ----
        if (k0 + BK < K_TOT) {
            #pragma unroll
            for (int p = 0; p < 8; ++p) {
                const int row = srow + p * 16;
                pa[p] = *reinterpret_cast<const float4*>(
                    x + (size_t)(bm + row) * K_TOT + k0 + BK + scol);
            }
        }

        // ---- fragments + MFMA (split by kk to bound reg pressure) ----
        #pragma unroll
        for (int kk = 0; kk < 2; ++kk) {
            bf16x8 af[4], bfr[4];
            #pragma unroll
            for (int mi = 0; mi < 4; ++mi) {
                const int r = wm + mi * 16 + frow;
                const int c = (kk * 32 + fk) ^ ((r & 7) << 3);
                af[mi] = *reinterpret_cast<bf16x8*>(&As[r][c]);
            }
            #pragma unroll
            for (int ni = 0; ni < 4; ++ni) {
                const int r = wn + ni * 16 + frow;
                const int c = (kk * 32 + fk) ^ ((r & 7) << 3);
                bfr[ni] = *reinterpret_cast<bf16x8*>(&Bs[r][c]);
            }
            #pragma unroll
            for (int mi = 0; mi < 4; ++mi)
                #pragma unroll
                for (int ni = 0; ni < 4; ++ni)
                    acc[mi][ni] = __builtin_amdgcn_mfma_f32_16x16x32_bf16(
                        af[mi], bfr[ni], acc[mi][ni], 0, 0, 0);
        }
        __syncthreads();
    }

    // ---- epilogue: C/D map col=lane&15, row=(lane>>4)*4+i ----
    #pragma unroll
    for (int ni = 0; ni < 4; ++ni) {
        const int c  = bn + wn + ni * 16 + (lane & 15);
        const float bv = bias[c];
        #pragma unroll
        for (int mi = 0; mi < 4; ++mi) {
            const int r0 = bm + wm + mi * 16 + (lane >> 4) * 4;
            #pragma unroll
            for (int i = 0; i < 4; ++i)
                out[(size_t)(r0 + i) * N_TOT + c] = acc[mi][ni][i] + bv;
        }
    }
}

extern "C" void kernel_launch(void* const* d_in, const int* in_sizes, int n_in,
                              void* d_out, int out_size, void* d_ws, size_t ws_size,
                              hipStream_t stream) {
    const float* x    = (const float*)d_in[0];
    const float* phi  = (const float*)d_in[1];
    const float* W    = (const float*)d_in[2];
    const float* bias = (const float*)d_in[3];
    float* out = (float*)d_out;

    const int grid = (M_TOT / BM) * (N_TOT / BN);   // 2048
    const size_t ws_need = (size_t)N_TOT * K_TOT * sizeof(bf16_t);  // 512 KB

    if (ws_size >= ws_need) {
        bf16_t* Wws = (bf16_t*)d_ws;
        convert_W<<<(N_TOT * K_TOT / 8) / 256, 256, 0, stream>>>(W, Wws);
        qattn_fused_gemm<true><<<grid, 256, 0, stream>>>(x, phi, W, Wws, bias, out);
    } else {
        qattn_fused_gemm<false><<<grid, 256, 0, stream>>>(x, phi, W, nullptr, bias, out);
    }
}